// Round 6
// baseline (422.367 us; speedup 1.0000x reference)
//
#include <hip/hip_runtime.h>

#define NN 50000
#define EE 800000
#define NB ((NN + 1023) / 1024) // 49

typedef __attribute__((ext_vector_type(8))) short short8;
typedef __attribute__((ext_vector_type(16))) float f32x16;

static __device__ __forceinline__ unsigned short f2bf(float f) {
    unsigned u = __float_as_uint(f);
    u += 0x7fffu + ((u >> 16) & 1u);
    return (unsigned short)(u >> 16);
}
static __device__ __forceinline__ unsigned pack2(float a, float b) {
    return (unsigned)f2bf(a) | ((unsigned)f2bf(b) << 16);
}
static __device__ __forceinline__ f32x16 splat16(float v) {
    f32x16 r;
    #pragma unroll
    for (int i = 0; i < 16; ++i) r[i] = v;
    return r;
}

union U8 { short8 v; uint2 u[2]; };

// read an 8-bf16 MFMA fragment: elems [0..3] at k0, [4..7] at k0+8
static __device__ __forceinline__ short8 ldsfrag(const unsigned short* rowbase, int k0) {
    U8 t;
    t.u[0] = *(const uint2*)(rowbase + k0);
    t.u[1] = *(const uint2*)(rowbase + k0 + 8);
    return t.v;
}

// ---------------------------------------------------------------------------
// Kernel 1: Qh/Kh/Vh via MFMA. Block = 256 thr = 4 waves x 32 rows.
// ---------------------------------------------------------------------------
__global__ __launch_bounds__(256) void qkv_mfma_kernel(
    const float* __restrict__ x,
    const float* __restrict__ WQ, const float* __restrict__ WK, const float* __restrict__ WV,
    float* __restrict__ Qh, float* __restrict__ Kh, float* __restrict__ Vh)
{
    __shared__ unsigned short s_wq[64][66];
    __shared__ unsigned short s_wk[64][66];
    __shared__ unsigned short s_wv[64][66];

    int tid = threadIdx.x;
    #pragma unroll
    for (int t = 0; t < 16; ++t) {
        int idx = t * 256 + tid;
        int r = idx >> 6, c = idx & 63;
        s_wq[r][c] = f2bf(WQ[idx]);
        s_wk[r][c] = f2bf(WK[idx]);
        s_wv[r][c] = f2bf(WV[idx]);
    }
    __syncthreads();

    int wid = tid >> 6, lane = tid & 63;
    int m0 = blockIdx.x * 128 + wid * 32;
    int lo5 = lane & 31, hi = lane >> 5;

    int rowi = m0 + lo5;
    const float* arow = x + (size_t)(rowi < NN ? rowi : NN - 1) * 64;
    short8 af[4];
    #pragma unroll
    for (int ks = 0; ks < 4; ++ks) {
        int k0 = ks * 16 + hi * 4;
        float4 a0 = *(const float4*)(arow + k0);
        float4 a1 = *(const float4*)(arow + k0 + 8);
        U8 t;
        t.u[0] = make_uint2(pack2(a0.x, a0.y), pack2(a0.z, a0.w));
        t.u[1] = make_uint2(pack2(a1.x, a1.y), pack2(a1.z, a1.w));
        af[ks] = t.v;
    }

    #pragma unroll
    for (int nt = 0; nt < 2; ++nt) {
        int n = nt * 32 + lo5;
        f32x16 cQ = splat16(0.f), cK = splat16(0.f), cV = splat16(0.f);
        #pragma unroll
        for (int ks = 0; ks < 4; ++ks) {
            int k0 = ks * 16 + hi * 4;
            cQ = __builtin_amdgcn_mfma_f32_32x32x16_bf16(af[ks], ldsfrag(s_wq[n], k0), cQ, 0, 0, 0);
            cK = __builtin_amdgcn_mfma_f32_32x32x16_bf16(af[ks], ldsfrag(s_wk[n], k0), cK, 0, 0, 0);
            cV = __builtin_amdgcn_mfma_f32_32x32x16_bf16(af[ks], ldsfrag(s_wv[n], k0), cV, 0, 0, 0);
        }
        #pragma unroll
        for (int r = 0; r < 16; ++r) {
            int m = (r & 3) + 8 * (r >> 2) + 4 * hi;
            int gm = m0 + m;
            if (gm < NN) {
                Qh[(size_t)gm * 64 + n] = cQ[r];
                Kh[(size_t)gm * 64 + n] = cK[r];
                Vh[(size_t)gm * 64 + n] = cV[r];
            }
        }
    }
}

// ---------------------------------------------------------------------------
// CSR build: histogram -> hierarchical scan -> scatter (combined int2 + inv)
// ---------------------------------------------------------------------------
__global__ __launch_bounds__(256) void hist_kernel(const int* __restrict__ eidx,
                                                   int* __restrict__ cnt)
{
    int e = blockIdx.x * blockDim.x + threadIdx.x;
    atomicAdd(&cnt[eidx[e]], 1);
}

__global__ __launch_bounds__(1024) void scan1_kernel(const int* __restrict__ cnt,
                                                     int* __restrict__ rowstart,
                                                     int* __restrict__ bsum)
{
    __shared__ int buf[1024];
    int tid = threadIdx.x;
    int i = blockIdx.x * 1024 + tid;
    int v = (i < NN) ? cnt[i] : 0;
    buf[tid] = v;
    __syncthreads();
    for (int off = 1; off < 1024; off <<= 1) {
        int t = (tid >= off) ? buf[tid - off] : 0;
        __syncthreads();
        buf[tid] += t;
        __syncthreads();
    }
    if (i < NN) rowstart[i] = buf[tid] - v;
    if (tid == 1023) bsum[blockIdx.x] = buf[1023];
}

__global__ __launch_bounds__(64) void scan2_kernel(const int* __restrict__ bsum,
                                                   int* __restrict__ boff,
                                                   int* __restrict__ rowstart)
{
    int lane = threadIdx.x;
    int v = (lane < NB) ? bsum[lane] : 0;
    int s = v;
    #pragma unroll
    for (int off = 1; off < 64; off <<= 1) {
        int t = __shfl_up(s, off, 64);
        if (lane >= off) s += t;
    }
    if (lane < NB) boff[lane] = s - v;
    if (lane == 63) rowstart[NN] = s;
}

__global__ __launch_bounds__(1024) void scan3_kernel(int* __restrict__ rowstart,
                                                     const int* __restrict__ boff,
                                                     int* __restrict__ cursor)
{
    int i = blockIdx.x * 1024 + threadIdx.x;
    if (i < NN) {
        int r = rowstart[i] + boff[blockIdx.x];
        rowstart[i] = r;
        cursor[i] = r;
    }
}

__global__ __launch_bounds__(256) void scatter_kernel(const int* __restrict__ eidx,
                                                      int* __restrict__ cursor,
                                                      int2* __restrict__ edges_csr,
                                                      int* __restrict__ inv)
{
    int e = blockIdx.x * blockDim.x + threadIdx.x;
    int dst = eidx[e];
    int pos = atomicAdd(&cursor[dst], 1);
    edges_csr[pos] = make_int2(e, eidx[EE + e]);
    inv[e] = pos;
}

// ---------------------------------------------------------------------------
// Kernel 2: per-edge MFMA pass, TRANSPOSED GEMMs: D[j(feature)][e(edge)].
//   8 waves x 32 edges = 256 edges/block, one tile per block (3125 blocks).
//   mfma(A=W_frag, B=edge_frag): lane = edge column; the transposed C-layout
//   puts 16 features of the lane's own edge in-register = exactly the
//   B-fragment pattern for the next GEMM -> NO conn LDS round-trip.
// ---------------------------------------------------------------------------
__global__ __launch_bounds__(512) void edge_mfma_kernel(
    const float* __restrict__ eattr, const int* __restrict__ eidx,
    const int* __restrict__ inv,
    const float* __restrict__ WEw, const float* __restrict__ WEb, const float* __restrict__ bEb,
    const float* __restrict__ WEo, const float* __restrict__ bEo, const float* __restrict__ Aw,
    const float* __restrict__ Qh, const float* __restrict__ Kh,
    float* __restrict__ Eo_out, float* __restrict__ exbuf)
{
    __shared__ unsigned short s_wew[64][66];
    __shared__ unsigned short s_web[64][66];
    __shared__ unsigned short s_weo[64][66];
    __shared__ unsigned short s_baw[32][66];   // block-diagonal Aw: A[h][k]
    __shared__ float s_bEb[64];
    __shared__ float s_bEo[64];

    int tid = threadIdx.x;
    #pragma unroll
    for (int t = 0; t < 8; ++t) {
        int idx = t * 512 + tid;
        int r = idx >> 6, c = idx & 63;
        s_wew[r][c] = f2bf(WEw[idx]);
        s_web[r][c] = f2bf(WEb[idx]);
        s_weo[r][c] = f2bf(WEo[idx]);
    }
    #pragma unroll
    for (int t = 0; t < 4; ++t) {
        int idx = t * 512 + tid;
        int n = idx >> 6, k = idx & 63;
        s_baw[n][k] = (n == (k >> 3)) ? f2bf(Aw[(k & 7) * 8 + n]) : (unsigned short)0;
    }
    if (tid < 64) { s_bEb[tid] = bEb[tid]; s_bEo[tid] = bEo[tid]; }
    __syncthreads();

    int wid = tid >> 6, lane = tid & 63;
    int lo5 = lane & 31, hi = lane >> 5;

    int e = blockIdx.x * 256 + wid * 32 + lo5;   // this lane's edge
    int dst = eidx[e], src = eidx[EE + e], pos = inv[e];

    // eattr B-fragments (lane = edge column)
    short8 af[4];
    {
        const float* arow = eattr + (size_t)e * 64;
        #pragma unroll
        for (int ks = 0; ks < 4; ++ks) {
            int k0 = ks * 16 + hi * 4;
            float4 a0 = *(const float4*)(arow + k0);
            float4 a1 = *(const float4*)(arow + k0 + 8);
            U8 t;
            t.u[0] = make_uint2(pack2(a0.x, a0.y), pack2(a0.z, a0.w));
            t.u[1] = make_uint2(pack2(a1.x, a1.y), pack2(a1.z, a1.w));
            af[ks] = t.v;
        }
    }

    // MFMA1 (Ew, Eb, transposed) + epilogue -> conn -> ca fragments in-register
    short8 ca[4];
    #pragma unroll
    for (int nt = 0; nt < 2; ++nt) {
        // qk for this lane's edge at features j = 32nt + 8r4 + 4hi + c (float4)
        float qk[16];
        #pragma unroll
        for (int r4 = 0; r4 < 4; ++r4) {
            int off = nt * 32 + r4 * 8 + hi * 4;
            float4 qv = *(const float4*)(Qh + (size_t)dst * 64 + off);
            float4 kv = *(const float4*)(Kh + (size_t)src * 64 + off);
            qk[r4 * 4 + 0] = qv.x + kv.x;
            qk[r4 * 4 + 1] = qv.y + kv.y;
            qk[r4 * 4 + 2] = qv.z + kv.z;
            qk[r4 * 4 + 3] = qv.w + kv.w;
        }

        f32x16 cEw = splat16(0.f), cEb = splat16(0.f);
        #pragma unroll
        for (int ks = 0; ks < 4; ++ks) {
            int k0 = ks * 16 + hi * 4;
            short8 wf = ldsfrag(s_wew[nt * 32 + lo5], k0);
            short8 bf = ldsfrag(s_web[nt * 32 + lo5], k0);
            cEw = __builtin_amdgcn_mfma_f32_32x32x16_bf16(wf, af[ks], cEw, 0, 0, 0);
            cEb = __builtin_amdgcn_mfma_f32_32x32x16_bf16(bf, af[ks], cEb, 0, 0, 0);
        }

        float conn[16];
        #pragma unroll
        for (int r4 = 0; r4 < 4; ++r4) {
            float4 bb = *(const float4*)&s_bEb[nt * 32 + r4 * 8 + hi * 4];
            float bbv[4] = {bb.x, bb.y, bb.z, bb.w};
            #pragma unroll
            for (int c = 0; c < 4; ++c) {
                int r = r4 * 4 + c;
                float c1 = qk[r] * cEw[r];
                float c2 = copysignf(sqrtf(fabsf(c1)), c1);
                conn[r] = c2 + cEb[r] + bbv[c];
            }
        }

        // pack conn -> B-fragments for the next GEMMs (k-pattern matches)
        U8 t0, t1;
        t0.u[0] = make_uint2(pack2(conn[0], conn[1]), pack2(conn[2], conn[3]));
        t0.u[1] = make_uint2(pack2(conn[4], conn[5]), pack2(conn[6], conn[7]));
        t1.u[0] = make_uint2(pack2(conn[8], conn[9]), pack2(conn[10], conn[11]));
        t1.u[1] = make_uint2(pack2(conn[12], conn[13]), pack2(conn[14], conn[15]));
        ca[2 * nt + 0] = t0.v;
        ca[2 * nt + 1] = t1.v;
    }

    // score GEMM (block-diag Aw, transposed): D[h][e]; rows r=0..3 -> h = r+4hi
    {
        f32x16 cS = splat16(0.f);
        #pragma unroll
        for (int ks = 0; ks < 4; ++ks) {
            int k0 = ks * 16 + hi * 4;
            cS = __builtin_amdgcn_mfma_f32_32x32x16_bf16(ldsfrag(s_baw[lo5], k0), ca[ks], cS, 0, 0, 0);
        }
        float4 exv;
        exv.x = __expf(fminf(fmaxf(cS[0], -5.0f), 5.0f));
        exv.y = __expf(fminf(fmaxf(cS[1], -5.0f), 5.0f));
        exv.z = __expf(fminf(fmaxf(cS[2], -5.0f), 5.0f));
        exv.w = __expf(fminf(fmaxf(cS[3], -5.0f), 5.0f));
        *(float4*)(exbuf + (size_t)pos * 8 + hi * 4) = exv;   // CSR-ordered
    }

    // Eo GEMM (transposed) + bias -> per-lane row stores (16B chunks)
    #pragma unroll
    for (int nt = 0; nt < 2; ++nt) {
        f32x16 cO = splat16(0.f);
        #pragma unroll
        for (int ks = 0; ks < 4; ++ks) {
            int k0 = ks * 16 + hi * 4;
            cO = __builtin_amdgcn_mfma_f32_32x32x16_bf16(ldsfrag(s_weo[nt * 32 + lo5], k0), ca[ks], cO, 0, 0, 0);
        }
        #pragma unroll
        for (int r4 = 0; r4 < 4; ++r4) {
            int off = nt * 32 + r4 * 8 + hi * 4;
            float4 bo = *(const float4*)&s_bEo[off];
            float4 o = make_float4(cO[r4 * 4 + 0] + bo.x, cO[r4 * 4 + 1] + bo.y,
                                   cO[r4 * 4 + 2] + bo.z, cO[r4 * 4 + 3] + bo.w);
            *(float4*)(Eo_out + (size_t)e * 64 + off) = o;
        }
    }
}

// ---------------------------------------------------------------------------
// Kernel 3: node aggregation (CSR). One wave per node; lane = (h,d).
// ---------------------------------------------------------------------------
__global__ __launch_bounds__(256) void node_kernel(
    const int* __restrict__ rowstart, const int2* __restrict__ edges_csr,
    const float* __restrict__ exbuf, const float* __restrict__ Eo,
    const float* __restrict__ Vh, const float* __restrict__ BW,
    float* __restrict__ hout)
{
    int n = (blockIdx.x * blockDim.x + threadIdx.x) >> 6;
    int lane = threadIdx.x & 63;
    int h = lane >> 3, d = lane & 7;

    int beg = rowstart[n], end = rowstart[n + 1];
    float agg0 = 0.f, rv0 = 0.f, den0 = 0.f;
    float agg1 = 0.f, rv1 = 0.f, den1 = 0.f;
    int j = beg;
    for (; j + 1 < end; j += 2) {
        int2 ea = edges_csr[j];
        int2 eb = edges_csr[j + 1];
        float xa = exbuf[(size_t)j * 8 + h];
        float xb = exbuf[(size_t)(j + 1) * 8 + h];
        agg0 = fmaf(xa, Vh[(size_t)ea.y * 64 + lane], agg0);
        rv0  = fmaf(xa, Eo[(size_t)ea.x * 64 + lane], rv0);
        den0 += xa;
        agg1 = fmaf(xb, Vh[(size_t)eb.y * 64 + lane], agg1);
        rv1  = fmaf(xb, Eo[(size_t)eb.x * 64 + lane], rv1);
        den1 += xb;
    }
    if (j < end) {
        int2 ea = edges_csr[j];
        float xa = exbuf[(size_t)j * 8 + h];
        agg0 = fmaf(xa, Vh[(size_t)ea.y * 64 + lane], agg0);
        rv0  = fmaf(xa, Eo[(size_t)ea.x * 64 + lane], rv0);
        den0 += xa;
    }
    float agg = agg0 + agg1, rv = rv0 + rv1, den = den0 + den1;
    float inv = (den > 0.f) ? (1.0f / den) : 0.f;

    float acc = agg;
    #pragma unroll
    for (int dd = 0; dd < 8; ++dd) {
        float rvd = __shfl(rv, (h << 3) + dd, 64);
        acc = fmaf(rvd, BW[dd * 64 + (h << 3) + d], acc);
    }
    hout[(size_t)n * 64 + lane] = acc * inv;
}

// ---------------------------------------------------------------------------
extern "C" void kernel_launch(void* const* d_in, const int* in_sizes, int n_in,
                              void* d_out, int out_size, void* d_ws, size_t ws_size,
                              hipStream_t stream)
{
    const float* x    = (const float*)d_in[0];
    const float* ea   = (const float*)d_in[1];
    const int*   eidx = (const int*)  d_in[2];
    const float* WQ   = (const float*)d_in[3];
    const float* WK   = (const float*)d_in[4];
    const float* WV   = (const float*)d_in[5];
    const float* WEw  = (const float*)d_in[6];
    const float* WEb  = (const float*)d_in[7];
    const float* bEb  = (const float*)d_in[8];
    const float* WEo  = (const float*)d_in[9];
    const float* bEo  = (const float*)d_in[10];
    const float* Aw   = (const float*)d_in[11];
    const float* BW   = (const float*)d_in[12];

    float* hout   = (float*)d_out;
    float* Eo_out = hout + (size_t)NN * 64;

    float* Qh    = (float*)d_ws;
    float* Kh    = Qh + (size_t)NN * 64;
    float* Vh    = Kh + (size_t)NN * 64;
    float* exbuf = Vh + (size_t)NN * 64;
    int* cnt      = (int*)(exbuf + (size_t)EE * 8);  // doubles as cursor
    int* rowstart = cnt + NN;                        // NN+2 (pad to 8B align)
    int2* edges_csr = (int2*)(rowstart + NN + 2);
    int* invp     = (int*)(edges_csr + EE);
    int* bsum     = invp + EE;
    int* boff     = bsum + 64;

    hipMemsetAsync(cnt, 0, (size_t)NN * sizeof(int), stream);

    hist_kernel<<<EE / 256, 256, 0, stream>>>(eidx, cnt);
    scan1_kernel<<<NB, 1024, 0, stream>>>(cnt, rowstart, bsum);
    scan2_kernel<<<1, 64, 0, stream>>>(bsum, boff, rowstart);
    scan3_kernel<<<NB, 1024, 0, stream>>>(rowstart, boff, cnt);
    scatter_kernel<<<EE / 256, 256, 0, stream>>>(eidx, cnt, edges_csr, invp);

    qkv_mfma_kernel<<<(NN + 127) / 128, 256, 0, stream>>>(x, WQ, WK, WV, Qh, Kh, Vh);

    edge_mfma_kernel<<<EE / 256, 512, 0, stream>>>(ea, eidx, invp, WEw, WEb, bEb,
                                                   WEo, bEo, Aw, Qh, Kh, Eo_out, exbuf);

    node_kernel<<<(NN * 64) / 256, 256, 0, stream>>>(rowstart, edges_csr,
                                                     exbuf, Eo_out, Vh, BW, hout);
}

// Round 7
// 367.912 us; speedup vs baseline: 1.1480x; 1.1480x over previous
//
#include <hip/hip_runtime.h>

#define NN 50000
#define EE 800000
#define NT8 (EE / 256)          // 3125 tiles of 256 edges
#define NB ((NN + 1023) / 1024) // 49

typedef __attribute__((ext_vector_type(8))) short short8;
typedef __attribute__((ext_vector_type(16))) float f32x16;

static __device__ __forceinline__ unsigned short f2bf(float f) {
    unsigned u = __float_as_uint(f);
    u += 0x7fffu + ((u >> 16) & 1u);
    return (unsigned short)(u >> 16);
}
// packed f32x2 -> bf16x2 (single HW instruction, RTNE)
static __device__ __forceinline__ unsigned cvt_pk(float lo, float hi) {
    unsigned r;
    asm("v_cvt_pk_bf16_f32 %0, %1, %2" : "=v"(r) : "v"(lo), "v"(hi));
    return r;
}
static __device__ __forceinline__ float lo_f(unsigned u) { return __uint_as_float(u << 16); }
static __device__ __forceinline__ float hi_f(unsigned u) { return __uint_as_float(u & 0xffff0000u); }
static __device__ __forceinline__ f32x16 splat16(float v) {
    f32x16 r;
    #pragma unroll
    for (int i = 0; i < 16; ++i) r[i] = v;
    return r;
}

union U8 { short8 v; uint2 u[2]; };

// read an 8-bf16 MFMA fragment: elems [0..3] at k0, [4..7] at k0+8
static __device__ __forceinline__ short8 ldsfrag(const unsigned short* rowbase, int k0) {
    U8 t;
    t.u[0] = *(const uint2*)(rowbase + k0);
    t.u[1] = *(const uint2*)(rowbase + k0 + 8);
    return t.v;
}

// ---------------------------------------------------------------------------
// Kernel 1: Qh/Kh/Vh via MFMA. Block = 256 thr = 4 waves x 32 rows.
// ---------------------------------------------------------------------------
__global__ __launch_bounds__(256) void qkv_mfma_kernel(
    const float* __restrict__ x,
    const float* __restrict__ WQ, const float* __restrict__ WK, const float* __restrict__ WV,
    float* __restrict__ Qh, float* __restrict__ Kh, float* __restrict__ Vh)
{
    __shared__ unsigned short s_wq[64][68];
    __shared__ unsigned short s_wk[64][68];
    __shared__ unsigned short s_wv[64][68];

    int tid = threadIdx.x;
    #pragma unroll
    for (int t = 0; t < 8; ++t) {
        int idx = (t * 256 + tid) * 2;
        int r = idx >> 6, c = idx & 63;
        float2 w = *(const float2*)(WQ + idx);
        *(unsigned*)&s_wq[r][c] = cvt_pk(w.x, w.y);
        w = *(const float2*)(WK + idx);
        *(unsigned*)&s_wk[r][c] = cvt_pk(w.x, w.y);
        w = *(const float2*)(WV + idx);
        *(unsigned*)&s_wv[r][c] = cvt_pk(w.x, w.y);
    }
    __syncthreads();

    int wid = tid >> 6, lane = tid & 63;
    int m0 = blockIdx.x * 128 + wid * 32;
    int lo5 = lane & 31, hi = lane >> 5;

    int rowi = m0 + lo5;
    const float* arow = x + (size_t)(rowi < NN ? rowi : NN - 1) * 64;
    short8 af[4];
    #pragma unroll
    for (int ks = 0; ks < 4; ++ks) {
        int k0 = ks * 16 + hi * 4;
        float4 a0 = *(const float4*)(arow + k0);
        float4 a1 = *(const float4*)(arow + k0 + 8);
        U8 t;
        t.u[0] = make_uint2(cvt_pk(a0.x, a0.y), cvt_pk(a0.z, a0.w));
        t.u[1] = make_uint2(cvt_pk(a1.x, a1.y), cvt_pk(a1.z, a1.w));
        af[ks] = t.v;
    }

    #pragma unroll
    for (int nt = 0; nt < 2; ++nt) {
        int n = nt * 32 + lo5;
        f32x16 cQ = splat16(0.f), cK = splat16(0.f), cV = splat16(0.f);
        #pragma unroll
        for (int ks = 0; ks < 4; ++ks) {
            int k0 = ks * 16 + hi * 4;
            cQ = __builtin_amdgcn_mfma_f32_32x32x16_bf16(af[ks], ldsfrag(s_wq[n], k0), cQ, 0, 0, 0);
            cK = __builtin_amdgcn_mfma_f32_32x32x16_bf16(af[ks], ldsfrag(s_wk[n], k0), cK, 0, 0, 0);
            cV = __builtin_amdgcn_mfma_f32_32x32x16_bf16(af[ks], ldsfrag(s_wv[n], k0), cV, 0, 0, 0);
        }
        #pragma unroll
        for (int r = 0; r < 16; ++r) {
            int m = (r & 3) + 8 * (r >> 2) + 4 * hi;
            int gm = m0 + m;
            if (gm < NN) {
                Qh[(size_t)gm * 64 + n] = cQ[r];
                Kh[(size_t)gm * 64 + n] = cK[r];
                Vh[(size_t)gm * 64 + n] = cV[r];
            }
        }
    }
}

// ---------------------------------------------------------------------------
// CSR build: histogram -> hierarchical scan -> scatter (combined int2 + inv)
// ---------------------------------------------------------------------------
__global__ __launch_bounds__(256) void hist_kernel(const int* __restrict__ eidx,
                                                   int* __restrict__ cnt)
{
    int e = blockIdx.x * blockDim.x + threadIdx.x;
    atomicAdd(&cnt[eidx[e]], 1);
}

__global__ __launch_bounds__(1024) void scan1_kernel(const int* __restrict__ cnt,
                                                     int* __restrict__ rowstart,
                                                     int* __restrict__ bsum)
{
    __shared__ int buf[1024];
    int tid = threadIdx.x;
    int i = blockIdx.x * 1024 + tid;
    int v = (i < NN) ? cnt[i] : 0;
    buf[tid] = v;
    __syncthreads();
    for (int off = 1; off < 1024; off <<= 1) {
        int t = (tid >= off) ? buf[tid - off] : 0;
        __syncthreads();
        buf[tid] += t;
        __syncthreads();
    }
    if (i < NN) rowstart[i] = buf[tid] - v;
    if (tid == 1023) bsum[blockIdx.x] = buf[1023];
}

__global__ __launch_bounds__(64) void scan2_kernel(const int* __restrict__ bsum,
                                                   int* __restrict__ boff,
                                                   int* __restrict__ rowstart)
{
    int lane = threadIdx.x;
    int v = (lane < NB) ? bsum[lane] : 0;
    int s = v;
    #pragma unroll
    for (int off = 1; off < 64; off <<= 1) {
        int t = __shfl_up(s, off, 64);
        if (lane >= off) s += t;
    }
    if (lane < NB) boff[lane] = s - v;
    if (lane == 63) rowstart[NN] = s;
}

__global__ __launch_bounds__(1024) void scan3_kernel(int* __restrict__ rowstart,
                                                     const int* __restrict__ boff,
                                                     int* __restrict__ cursor)
{
    int i = blockIdx.x * 1024 + threadIdx.x;
    if (i < NN) {
        int r = rowstart[i] + boff[blockIdx.x];
        rowstart[i] = r;
        cursor[i] = r;
    }
}

__global__ __launch_bounds__(256) void scatter_kernel(const int* __restrict__ eidx,
                                                      int* __restrict__ cursor,
                                                      int2* __restrict__ edges_csr,
                                                      int* __restrict__ inv)
{
    int e = blockIdx.x * blockDim.x + threadIdx.x;
    int dst = eidx[e];
    int pos = atomicAdd(&cursor[dst], 1);
    edges_csr[pos] = make_int2(e, eidx[EE + e]);
    inv[e] = pos;
}

// ---------------------------------------------------------------------------
// Kernel 2: per-edge MFMA pass, TRANSPOSED GEMMs, grid-stride.
//   512 thr = 8 waves x 32 edges/tile; ~6 tiles per block (weights staged 1x).
//   qk gathered COALESCED (float4) into per-wave bf16 LDS, read back per-lane.
//   conn stays in-register as the next GEMM's B-fragments (no LDS roundtrip).
// ---------------------------------------------------------------------------
__global__ __launch_bounds__(512) void edge_mfma_kernel(
    const float* __restrict__ eattr, const int* __restrict__ eidx,
    const int* __restrict__ inv,
    const float* __restrict__ WEw, const float* __restrict__ WEb, const float* __restrict__ bEb,
    const float* __restrict__ WEo, const float* __restrict__ bEo, const float* __restrict__ Aw,
    const float* __restrict__ Qh, const float* __restrict__ Kh,
    float* __restrict__ Eo_out, float* __restrict__ exbuf)
{
    __shared__ unsigned short s_wew[64][68];
    __shared__ unsigned short s_web[64][68];
    __shared__ unsigned short s_weo[64][68];
    __shared__ unsigned short s_baw[32][68];    // block-diagonal Aw (A-operand)
    __shared__ unsigned short s_qk[8][32][68];  // per-wave qk staging (bf16)
    __shared__ float s_bEb[64];
    __shared__ float s_bEo[64];

    int tid = threadIdx.x;
    #pragma unroll
    for (int t = 0; t < 4; ++t) {
        int idx = (t * 512 + tid) * 2;
        int r = idx >> 6, c = idx & 63;
        float2 w = *(const float2*)(WEw + idx);
        *(unsigned*)&s_wew[r][c] = cvt_pk(w.x, w.y);
        w = *(const float2*)(WEb + idx);
        *(unsigned*)&s_web[r][c] = cvt_pk(w.x, w.y);
        w = *(const float2*)(WEo + idx);
        *(unsigned*)&s_weo[r][c] = cvt_pk(w.x, w.y);
    }
    #pragma unroll
    for (int t = 0; t < 4; ++t) {
        int idx = t * 512 + tid;
        int n = idx >> 6, k = idx & 63;
        s_baw[n][k] = (n == (k >> 3)) ? f2bf(Aw[(k & 7) * 8 + n]) : (unsigned short)0;
    }
    if (tid < 64) { s_bEb[tid] = bEb[tid]; s_bEo[tid] = bEo[tid]; }
    __syncthreads();

    int wid = tid >> 6, lane = tid & 63;
    int lo5 = lane & 31, hi = lane >> 5;
    int mm = lane >> 4;          // 0..3: edge-within-quad for the gather
    int cc = (lane & 15) * 4;    // feature chunk for the gather

    for (int tile = blockIdx.x; tile < NT8; tile += gridDim.x) {
        int e0 = tile * 256 + wid * 32;
        int e  = e0 + lo5;                 // this lane's edge
        int pos = inv[e];

        // coalesced qk gather -> s_qk[wid] (16-lane groups, float4 loads)
        #pragma unroll
        for (int t = 0; t < 8; ++t) {
            int m = t * 4 + mm;
            int em = e0 + m;
            int dst = eidx[em], src = eidx[EE + em];
            float4 q = *(const float4*)(Qh + (size_t)dst * 64 + cc);
            float4 k = *(const float4*)(Kh + (size_t)src * 64 + cc);
            *(uint2*)&s_qk[wid][m][cc] =
                make_uint2(cvt_pk(q.x + k.x, q.y + k.y), cvt_pk(q.z + k.z, q.w + k.w));
        }

        // eattr B-fragments (lane = its own edge)
        short8 af[4];
        {
            const float* arow = eattr + (size_t)e * 64;
            #pragma unroll
            for (int ks = 0; ks < 4; ++ks) {
                int k0 = ks * 16 + hi * 4;
                float4 a0 = *(const float4*)(arow + k0);
                float4 a1 = *(const float4*)(arow + k0 + 8);
                U8 t;
                t.u[0] = make_uint2(cvt_pk(a0.x, a0.y), cvt_pk(a0.z, a0.w));
                t.u[1] = make_uint2(cvt_pk(a1.x, a1.y), cvt_pk(a1.z, a1.w));
                af[ks] = t.v;
            }
        }
        // s_qk is per-wave and DS ops are program-ordered within a wave:
        // this wave's reads below see its own writes above (R3/R4-verified).

        // MFMA1 (Ew, Eb transposed) + epilogue -> conn -> ca in-register
        short8 ca[4];
        #pragma unroll
        for (int nt = 0; nt < 2; ++nt) {
            f32x16 cEw = splat16(0.f), cEb = splat16(0.f);
            #pragma unroll
            for (int ks = 0; ks < 4; ++ks) {
                int k0 = ks * 16 + hi * 4;
                short8 wf = ldsfrag(s_wew[nt * 32 + lo5], k0);
                short8 bf = ldsfrag(s_web[nt * 32 + lo5], k0);
                cEw = __builtin_amdgcn_mfma_f32_32x32x16_bf16(wf, af[ks], cEw, 0, 0, 0);
                cEb = __builtin_amdgcn_mfma_f32_32x32x16_bf16(bf, af[ks], cEb, 0, 0, 0);
            }
            float conn[16];
            #pragma unroll
            for (int r4 = 0; r4 < 4; ++r4) {
                int off = nt * 32 + r4 * 8 + hi * 4;
                uint2 qraw = *(const uint2*)&s_qk[wid][lo5][off];
                float4 bb = *(const float4*)&s_bEb[off];
                float qk[4] = {lo_f(qraw.x), hi_f(qraw.x), lo_f(qraw.y), hi_f(qraw.y)};
                float bbv[4] = {bb.x, bb.y, bb.z, bb.w};
                #pragma unroll
                for (int c = 0; c < 4; ++c) {
                    int r = r4 * 4 + c;
                    float c1 = qk[c] * cEw[r];
                    float c2 = copysignf(sqrtf(fabsf(c1)), c1);
                    conn[r] = c2 + cEb[r] + bbv[c];
                }
            }
            U8 t0, t1;
            t0.u[0] = make_uint2(cvt_pk(conn[0], conn[1]), cvt_pk(conn[2], conn[3]));
            t0.u[1] = make_uint2(cvt_pk(conn[4], conn[5]), cvt_pk(conn[6], conn[7]));
            t1.u[0] = make_uint2(cvt_pk(conn[8], conn[9]), cvt_pk(conn[10], conn[11]));
            t1.u[1] = make_uint2(cvt_pk(conn[12], conn[13]), cvt_pk(conn[14], conn[15]));
            ca[2 * nt + 0] = t0.v;
            ca[2 * nt + 1] = t1.v;
        }

        // score GEMM (block-diag Aw): D[h][edge]; rows 0..3 -> h = hi*4 + r
        {
            f32x16 cS = splat16(0.f);
            #pragma unroll
            for (int ks = 0; ks < 4; ++ks) {
                int k0 = ks * 16 + hi * 4;
                cS = __builtin_amdgcn_mfma_f32_32x32x16_bf16(ldsfrag(s_baw[lo5], k0), ca[ks], cS, 0, 0, 0);
            }
            float4 exv;
            exv.x = __expf(fminf(fmaxf(cS[0], -5.0f), 5.0f));
            exv.y = __expf(fminf(fmaxf(cS[1], -5.0f), 5.0f));
            exv.z = __expf(fminf(fmaxf(cS[2], -5.0f), 5.0f));
            exv.w = __expf(fminf(fmaxf(cS[3], -5.0f), 5.0f));
            *(float4*)(exbuf + (size_t)pos * 8 + hi * 4) = exv;   // CSR-ordered
        }

        // Eo GEMM (transposed) + bias -> per-lane row stores (16B chunks)
        #pragma unroll
        for (int nt = 0; nt < 2; ++nt) {
            f32x16 cO = splat16(0.f);
            #pragma unroll
            for (int ks = 0; ks < 4; ++ks) {
                int k0 = ks * 16 + hi * 4;
                cO = __builtin_amdgcn_mfma_f32_32x32x16_bf16(ldsfrag(s_weo[nt * 32 + lo5], k0), ca[ks], cO, 0, 0, 0);
            }
            #pragma unroll
            for (int r4 = 0; r4 < 4; ++r4) {
                int off = nt * 32 + r4 * 8 + hi * 4;
                float4 bo = *(const float4*)&s_bEo[off];
                float4 o = make_float4(cO[r4 * 4 + 0] + bo.x, cO[r4 * 4 + 1] + bo.y,
                                       cO[r4 * 4 + 2] + bo.z, cO[r4 * 4 + 3] + bo.w);
                *(float4*)(Eo_out + (size_t)e * 64 + off) = o;
            }
        }
    }
}

// ---------------------------------------------------------------------------
// Kernel 3: node aggregation (CSR). One wave per node; lane = (h,d).
// ---------------------------------------------------------------------------
__global__ __launch_bounds__(256) void node_kernel(
    const int* __restrict__ rowstart, const int2* __restrict__ edges_csr,
    const float* __restrict__ exbuf, const float* __restrict__ Eo,
    const float* __restrict__ Vh, const float* __restrict__ BW,
    float* __restrict__ hout)
{
    int n = (blockIdx.x * blockDim.x + threadIdx.x) >> 6;
    int lane = threadIdx.x & 63;
    int h = lane >> 3, d = lane & 7;

    int beg = rowstart[n], end = rowstart[n + 1];
    float agg0 = 0.f, rv0 = 0.f, den0 = 0.f;
    float agg1 = 0.f, rv1 = 0.f, den1 = 0.f;
    int j = beg;
    for (; j + 1 < end; j += 2) {
        int2 ea = edges_csr[j];
        int2 eb = edges_csr[j + 1];
        float xa = exbuf[(size_t)j * 8 + h];
        float xb = exbuf[(size_t)(j + 1) * 8 + h];
        agg0 = fmaf(xa, Vh[(size_t)ea.y * 64 + lane], agg0);
        rv0  = fmaf(xa, Eo[(size_t)ea.x * 64 + lane], rv0);
        den0 += xa;
        agg1 = fmaf(xb, Vh[(size_t)eb.y * 64 + lane], agg1);
        rv1  = fmaf(xb, Eo[(size_t)eb.x * 64 + lane], rv1);
        den1 += xb;
    }
    if (j < end) {
        int2 ea = edges_csr[j];
        float xa = exbuf[(size_t)j * 8 + h];
        agg0 = fmaf(xa, Vh[(size_t)ea.y * 64 + lane], agg0);
        rv0  = fmaf(xa, Eo[(size_t)ea.x * 64 + lane], rv0);
        den0 += xa;
    }
    float agg = agg0 + agg1, rv = rv0 + rv1, den = den0 + den1;
    float inv = (den > 0.f) ? (1.0f / den) : 0.f;

    float acc = agg;
    #pragma unroll
    for (int dd = 0; dd < 8; ++dd) {
        float rvd = __shfl(rv, (h << 3) + dd, 64);
        acc = fmaf(rvd, BW[dd * 64 + (h << 3) + d], acc);
    }
    hout[(size_t)n * 64 + lane] = acc * inv;
}

// ---------------------------------------------------------------------------
extern "C" void kernel_launch(void* const* d_in, const int* in_sizes, int n_in,
                              void* d_out, int out_size, void* d_ws, size_t ws_size,
                              hipStream_t stream)
{
    const float* x    = (const float*)d_in[0];
    const float* ea   = (const float*)d_in[1];
    const int*   eidx = (const int*)  d_in[2];
    const float* WQ   = (const float*)d_in[3];
    const float* WK   = (const float*)d_in[4];
    const float* WV   = (const float*)d_in[5];
    const float* WEw  = (const float*)d_in[6];
    const float* WEb  = (const float*)d_in[7];
    const float* bEb  = (const float*)d_in[8];
    const float* WEo  = (const float*)d_in[9];
    const float* bEo  = (const float*)d_in[10];
    const float* Aw   = (const float*)d_in[11];
    const float* BW   = (const float*)d_in[12];

    float* hout   = (float*)d_out;
    float* Eo_out = hout + (size_t)NN * 64;

    float* Qh    = (float*)d_ws;
    float* Kh    = Qh + (size_t)NN * 64;
    float* Vh    = Kh + (size_t)NN * 64;
    float* exbuf = Vh + (size_t)NN * 64;
    int* cnt      = (int*)(exbuf + (size_t)EE * 8);  // doubles as cursor
    int* rowstart = cnt + NN;                        // NN+2 (pad to 8B align)
    int2* edges_csr = (int2*)(rowstart + NN + 2);
    int* invp     = (int*)(edges_csr + EE);
    int* bsum     = invp + EE;
    int* boff     = bsum + 64;

    hipMemsetAsync(cnt, 0, (size_t)NN * sizeof(int), stream);

    hist_kernel<<<EE / 256, 256, 0, stream>>>(eidx, cnt);
    scan1_kernel<<<NB, 1024, 0, stream>>>(cnt, rowstart, bsum);
    scan2_kernel<<<1, 64, 0, stream>>>(bsum, boff, rowstart);
    scan3_kernel<<<NB, 1024, 0, stream>>>(rowstart, boff, cnt);
    scatter_kernel<<<EE / 256, 256, 0, stream>>>(eidx, cnt, edges_csr, invp);

    qkv_mfma_kernel<<<(NN + 127) / 128, 256, 0, stream>>>(x, WQ, WK, WV, Qh, Kh, Vh);

    edge_mfma_kernel<<<512, 512, 0, stream>>>(ea, eidx, invp, WEw, WEb, bEb,
                                              WEo, bEo, Aw, Qh, Kh, Eo_out, exbuf);

    node_kernel<<<(NN * 64) / 256, 256, 0, stream>>>(rowstart, edges_csr,
                                                     exbuf, Eo_out, Vh, BW, hout);
}